// Round 3
// baseline (404.347 us; speedup 1.0000x reference)
//
#include <hip/hip_runtime.h>
#include <cstdint>
#include <cstddef>

// Problem constants (from reference)
#define BATCH 1024
#define S1 25
#define S2 10
#define FDIM 256
#define HDIM 128
#define NCLS 41
#define MAXDEG 128

typedef __attribute__((ext_vector_type(8))) short bf16x8;
typedef __attribute__((ext_vector_type(4))) float f32x4;

// ---------------- Threefry-2x32 (bit-exact vs JAX partitionable; r1-verified) --------
__host__ __device__ static inline void tf2x32(uint32_t k0, uint32_t k1,
                                              uint32_t c0, uint32_t c1,
                                              uint32_t& o0, uint32_t& o1) {
  const uint32_t ks2 = k0 ^ k1 ^ 0x1BD11BDAu;
  uint32_t x0 = c0 + k0, x1 = c1 + k1;
#define TFR(r) { x0 += x1; x1 = (x1 << (r)) | (x1 >> (32 - (r))); x1 ^= x0; }
  TFR(13) TFR(15) TFR(26) TFR(6)
  x0 += k1;  x1 += ks2 + 1u;
  TFR(17) TFR(29) TFR(16) TFR(24)
  x0 += ks2; x1 += k0 + 2u;
  TFR(13) TFR(15) TFR(26) TFR(6)
  x0 += k0;  x1 += k1 + 3u;
  TFR(17) TFR(29) TFR(16) TFR(24)
  x0 += k1;  x1 += ks2 + 4u;
  TFR(13) TFR(15) TFR(26) TFR(6)
  x0 += ks2; x1 += k0 + 5u;
#undef TFR
  o0 = x0; o1 = x1;
}

__device__ static inline uint32_t rand_bits_at(uint32_t kb0, uint32_t kb1, uint32_t j) {
  uint32_t o0, o1;
  tf2x32(kb0, kb1, 0u, j, o0, o1);
  return o0 ^ o1;
}

// fp32 -> bf16 (RNE) — values bit-preserved vs previous rounds
__device__ static inline ushort f2bf(float x) {
  uint32_t u = __float_as_uint(x);
  return (ushort)((u + 0x7fffu + ((u >> 16) & 1u)) >> 16);
}

// ================= K1: WbT transpose (2x128 rows of 256 bf16) ========================
__global__ __launch_bounds__(256)
void wprep_kernel(const float* __restrict__ Ws1, const float* __restrict__ Wn1,
                  ushort* __restrict__ WbT) {
  const int idx = blockIdx.x;            // 0..255 = h*128 + n
  const int h = idx >> 7, n = idx & 127;
  const float* W = h ? Wn1 : Ws1;
  WbT[(size_t)idx * FDIM + threadIdx.x] = f2bf(W[(size_t)threadIdx.x * HDIM + n]);
}

// ---------------- MFMA half: 32x256 (LDS A) @ 256x128 (global bf16 B) ----------------
// relu + column-mean over rows 0..24 (rows 25..31 are exact zeros) -> dst[0..127]
__device__ static inline void mfma_half(const ushort (*As)[32][40],
                                        const ushort* __restrict__ Bmat,
                                        float* __restrict__ dst,
                                        int wave, int lq, int lr) {
  f32x4 acc[2][2];
#pragma unroll
  for (int rt = 0; rt < 2; ++rt)
#pragma unroll
    for (int ct = 0; ct < 2; ++ct) acc[rt][ct] = (f32x4)(0.f);

#pragma unroll
  for (int k0 = 0; k0 < 8; ++k0) {
    bf16x8 b0 = *(const bf16x8*)(Bmat + (size_t)(wave * 32 + lr) * FDIM + k0 * 32 + lq * 8);
    bf16x8 b1 = *(const bf16x8*)(Bmat + (size_t)(wave * 32 + 16 + lr) * FDIM + k0 * 32 + lq * 8);
    bf16x8 a0 = *(const bf16x8*)&As[k0][lr][lq * 8];
    bf16x8 a1 = *(const bf16x8*)&As[k0][16 + lr][lq * 8];
    acc[0][0] = __builtin_amdgcn_mfma_f32_16x16x32_bf16(a0, b0, acc[0][0], 0, 0, 0);
    acc[0][1] = __builtin_amdgcn_mfma_f32_16x16x32_bf16(a0, b1, acc[0][1], 0, 0, 0);
    acc[1][0] = __builtin_amdgcn_mfma_f32_16x16x32_bf16(a1, b0, acc[1][0], 0, 0, 0);
    acc[1][1] = __builtin_amdgcn_mfma_f32_16x16x32_bf16(a1, b1, acc[1][1], 0, 0, 0);
  }

#pragma unroll
  for (int ct = 0; ct < 2; ++ct) {
    float s = 0.f;
#pragma unroll
    for (int rt = 0; rt < 2; ++rt)
#pragma unroll
      for (int r = 0; r < 4; ++r)
        s += fmaxf(acc[rt][ct][r], 0.f);
    s += __shfl_xor(s, 16, 64);
    s += __shfl_xor(s, 32, 64);
    if (lq == 0) dst[wave * 32 + ct * 16 + lr] = s * (1.f / S1);
  }
}

// ================= K2: mega kernel — one block per batch row, 5 blocks/CU ============
// LDS ~29.9 KB (single time-shared A-tile; n2m stashed in registers between halves)
// -> 5 resident blocks/CU = 20 waves/CU; all 1024 blocks co-resident on 256 CUs.
__global__ __launch_bounds__(256, 5)
void mega_kernel(const int* __restrict__ node_ids, const float* __restrict__ feat,
                 const int* __restrict__ adj, const ushort* __restrict__ WbT,
                 const float* __restrict__ Ws1, const float* __restrict__ Wn1,
                 const float* __restrict__ Ws2, const float* __restrict__ Wn2,
                 const float* __restrict__ Wp, const float* __restrict__ bp,
                 float* __restrict__ out,
                 uint32_t kb1_0, uint32_t kb1_1, uint32_t kb2_0, uint32_t kb2_1) {
  const int b = blockIdx.x;
  const int t = threadIdx.x;
  const int wave = t >> 6, lane = t & 63;
  const int lq = lane >> 4, lr = lane & 15;

  __shared__ int    hop1s[S1];
  __shared__ int    hop2s[S1 * S2];
  __shared__ ushort As[8][32][40];    // time-shared: f1 for half0, n2m for half1 (20.5 KB)
  __shared__ float  F0[FDIM];
  __shared__ float  N1[4][FDIM];      // per-wave n1 partials; N1[0] -> combined mean
  __shared__ float  H1M[2 * HDIM];
  __shared__ float  H0[2 * HDIM];
  __shared__ float  HN[2 * HDIM];
  __shared__ float  red[4];
  __shared__ float  lg[NCLS];
  __shared__ float  smx[2];

  const int nid = node_ids[b];

  // ---- A: merged hop1+hop2 sampling (hop1 recomputed redundantly per thread;
  //         the 10 same-s1 adj reads coalesce to one line) + f0 + A-pad zero ----
  if (t < S1 * S2) {
    const int s1 = t / S2;
    uint32_t c1 = rand_bits_at(kb1_0, kb1_1, (uint32_t)(b * S1 + s1)) & (MAXDEG - 1);
    const int h1 = adj[(size_t)nid * MAXDEG + c1];
    if (t == s1 * S2) hop1s[s1] = h1;
    uint32_t c2 = rand_bits_at(kb2_0, kb2_1, (uint32_t)(b * S1 * S2 + t)) & (MAXDEG - 1);
    hop2s[t] = adj[(size_t)h1 * MAXDEG + c2];
  }
  if (t < 64) ((float4*)F0)[t] = ((const float4*)(feat + (size_t)nid * FDIM))[t];
  {
    ushort4 z; z.x = 0; z.y = 0; z.z = 0; z.w = 0;
    for (int i = t; i < 448; i += 256) {   // rows 25..31 x 8 chunks x 8 q-slots
      const int rc = i >> 3, q = i & 7;
      const int r = 25 + (rc >> 3), ch = rc & 7;
      *(ushort4*)&As[ch][r][q * 4] = z;
    }
  }
  __syncthreads();

  // ---- C: gather f1 (-> LDS As + n1 partial) + f2 means (-> register stash nm) ----
  ushort4 nm[7];
  {
    float ax = 0.f, ay = 0.f, az = 0.f, aw = 0.f;
#pragma unroll
    for (int i = 0; i < 7; ++i) {
      const int s1 = wave + i * 4;
      if (s1 < S1) {
        const int rid1 = hop1s[s1];
        float4 v = ((const float4*)(feat + (size_t)rid1 * FDIM))[lane];
        float bx = 0.f, by = 0.f, bz = 0.f, bw = 0.f;
#pragma unroll
        for (int r = 0; r < S2; ++r) {
          const int rid = hop2s[s1 * S2 + r];
          float4 w = ((const float4*)(feat + (size_t)rid * FDIM))[lane];
          bx += w.x; by += w.y; bz += w.z; bw += w.w;
        }
        ax += v.x; ay += v.y; az += v.z; aw += v.w;
        ushort4 o1;
        o1.x = f2bf(v.x); o1.y = f2bf(v.y); o1.z = f2bf(v.z); o1.w = f2bf(v.w);
        *(ushort4*)&As[lane >> 3][s1][(lane & 7) * 4] = o1;
        const float inv2 = 1.f / S2;
        ushort4 o2;
        o2.x = f2bf(bx * inv2); o2.y = f2bf(by * inv2);
        o2.z = f2bf(bz * inv2); o2.w = f2bf(bw * inv2);
        nm[i] = o2;
      }
    }
    float4 p; p.x = ax; p.y = ay; p.z = az; p.w = aw;
    ((float4*)N1[wave])[lane] = p;
  }
  __syncthreads();

  // ---- D0: MFMA half 0 (A = f1) -> H1M[0..127] ----
  mfma_half(As, WbT, H1M, wave, lq, lr);
  __syncthreads();

  // ---- swap: n2m stash -> As; combine n1 mean (thread t owns column t) ----
#pragma unroll
  for (int i = 0; i < 7; ++i) {
    const int s1 = wave + i * 4;
    if (s1 < S1) *(ushort4*)&As[lane >> 3][s1][(lane & 7) * 4] = nm[i];
  }
  {
    const float s = N1[0][t] + N1[1][t] + N1[2][t] + N1[3][t];
    N1[0][t] = s * (1.f / S1);
  }
  __syncthreads();

  // ---- D1: MFMA half 1 (A = n2m) -> H1M[128..255] ----
  mfma_half(As, WbT + (size_t)HDIM * FDIM, H1M + HDIM, wave, lq, lr);
  __syncthreads();

  // ---- E: tail ----
  const int hh = t >> 7, c = t & 127;
  // phase 1: h0 = relu([f0@Ws1 ; n1m@Wn1]), column t
  {
    const float* W = hh ? Wn1 : Ws1;
    const float* Ap = hh ? N1[0] : F0;
    float acc = 0.f;
#pragma unroll 8
    for (int k4 = 0; k4 < 64; ++k4) {
      float4 a = ((const float4*)Ap)[k4];
      acc += a.x * W[(size_t)(k4 * 4 + 0) * HDIM + c]
           + a.y * W[(size_t)(k4 * 4 + 1) * HDIM + c]
           + a.z * W[(size_t)(k4 * 4 + 2) * HDIM + c]
           + a.w * W[(size_t)(k4 * 4 + 3) * HDIM + c];
    }
    H0[t] = fmaxf(acc, 0.f);
  }
  __syncthreads();

  // phase 2: h = [H0@Ws2 ; H1M@Wn2] (no act), column t
  float hv;
  {
    const float* W = hh ? Wn2 : Ws2;
    const float* Ap = hh ? H1M : H0;
    float acc = 0.f;
#pragma unroll 8
    for (int k4 = 0; k4 < 64; ++k4) {
      float4 a = ((const float4*)Ap)[k4];
      acc += a.x * W[(size_t)(k4 * 4 + 0) * HDIM + c]
           + a.y * W[(size_t)(k4 * 4 + 1) * HDIM + c]
           + a.z * W[(size_t)(k4 * 4 + 2) * HDIM + c]
           + a.w * W[(size_t)(k4 * 4 + 3) * HDIM + c];
    }
    hv = acc;
  }

  // phase 3: l2 normalize
  {
    float s = hv * hv;
#pragma unroll
    for (int off = 32; off; off >>= 1) s += __shfl_xor(s, off, 64);
    if (lane == 0) red[wave] = s;
  }
  __syncthreads();
  {
    const float scl = rsqrtf(fmaxf(red[0] + red[1] + red[2] + red[3], 1e-12f));
    HN[t] = hv * scl;
  }
  __syncthreads();

  // phase 4: logits — 41 dot-256's split across 4-lane groups, quad shfl reduce
  {
    const int g = t >> 2, q = t & 3;
    if (g < NCLS) {
      float s = 0.f;
#pragma unroll 8
      for (int k = 0; k < 64; ++k)
        s += HN[q * 64 + k] * Wp[(size_t)(q * 64 + k) * NCLS + g];
      s += __shfl_xor(s, 1, 64);
      s += __shfl_xor(s, 2, 64);
      if (q == 0) lg[g] = s + bp[g];
    }
  }
  __syncthreads();
  if (t == 0) {
    float m = -1e30f;
    for (int i = 0; i < NCLS; ++i) m = fmaxf(m, lg[i]);
    float ssum = 0.f;
    for (int i = 0; i < NCLS; ++i) ssum += expf(lg[i] - m);
    smx[0] = m; smx[1] = ssum;
  }
  __syncthreads();
  if (t < NCLS)
    out[(size_t)b * NCLS + t] = expf(lg[t] - smx[0]) / smx[1];
}

// ================= launch ============================================================
extern "C" void kernel_launch(void* const* d_in, const int* in_sizes, int n_in,
                              void* d_out, int out_size, void* d_ws, size_t ws_size,
                              hipStream_t stream) {
  const int*   node_ids = (const int*)d_in[0];
  const float* features = (const float*)d_in[1];
  const int*   adj      = (const int*)d_in[2];
  const float* Ws1      = (const float*)d_in[3];
  const float* Wn1      = (const float*)d_in[4];
  const float* Ws2      = (const float*)d_in[5];
  const float* Wn2      = (const float*)d_in[6];
  const float* Wp       = (const float*)d_in[7];
  const float* bp       = (const float*)d_in[8];
  float* out = (float*)d_out;

  ushort* WbT = (ushort*)d_ws;                // 2x128x256 bf16 (128 KB) — only ws use

  // JAX threefry key chain (bit-exact, r1-verified)
  uint32_t k1_0, k1_1, k2_0, k2_1, kb1_0, kb1_1, kb2_0, kb2_1;
  tf2x32(0u, 42u, 0u, 0u, k1_0, k1_1);
  tf2x32(0u, 42u, 0u, 1u, k2_0, k2_1);
  tf2x32(k1_0, k1_1, 0u, 1u, kb1_0, kb1_1);
  tf2x32(k2_0, k2_1, 0u, 1u, kb2_0, kb2_1);

  wprep_kernel<<<256, 256, 0, stream>>>(Ws1, Wn1, WbT);

  mega_kernel<<<BATCH, 256, 0, stream>>>(node_ids, features, adj, WbT,
                                         Ws1, Wn1, Ws2, Wn2, Wp, bp, out,
                                         kb1_0, kb1_1, kb2_0, kb2_1);
}

// Round 4
// 388.076 us; speedup vs baseline: 1.0419x; 1.0419x over previous
//
#include <hip/hip_runtime.h>
#include <cstdint>
#include <cstddef>

// Problem constants (from reference)
#define BATCH 1024
#define S1 25
#define S2 10
#define FDIM 256
#define HDIM 128
#define NCLS 41
#define MAXDEG 128

typedef __attribute__((ext_vector_type(8))) short bf16x8;
typedef __attribute__((ext_vector_type(4))) float f32x4;

// ---------------- Threefry-2x32 (bit-exact vs JAX partitionable; r1-verified) --------
__host__ __device__ static inline void tf2x32(uint32_t k0, uint32_t k1,
                                              uint32_t c0, uint32_t c1,
                                              uint32_t& o0, uint32_t& o1) {
  const uint32_t ks2 = k0 ^ k1 ^ 0x1BD11BDAu;
  uint32_t x0 = c0 + k0, x1 = c1 + k1;
#define TFR(r) { x0 += x1; x1 = (x1 << (r)) | (x1 >> (32 - (r))); x1 ^= x0; }
  TFR(13) TFR(15) TFR(26) TFR(6)
  x0 += k1;  x1 += ks2 + 1u;
  TFR(17) TFR(29) TFR(16) TFR(24)
  x0 += ks2; x1 += k0 + 2u;
  TFR(13) TFR(15) TFR(26) TFR(6)
  x0 += k0;  x1 += k1 + 3u;
  TFR(17) TFR(29) TFR(16) TFR(24)
  x0 += k1;  x1 += ks2 + 4u;
  TFR(13) TFR(15) TFR(26) TFR(6)
  x0 += ks2; x1 += k0 + 5u;
#undef TFR
  o0 = x0; o1 = x1;
}

__device__ static inline uint32_t rand_bits_at(uint32_t kb0, uint32_t kb1, uint32_t j) {
  uint32_t o0, o1;
  tf2x32(kb0, kb1, 0u, j, o0, o1);
  return o0 ^ o1;
}

// fp32 -> bf16 (RNE) — values bit-preserved vs previous rounds
__device__ static inline ushort f2bf(float x) {
  uint32_t u = __float_as_uint(x);
  return (ushort)((u + 0x7fffu + ((u >> 16) & 1u)) >> 16);
}

// ================= K1: WbT transpose (2x128 rows of 256 bf16) ========================
__global__ __launch_bounds__(256)
void wprep_kernel(const float* __restrict__ Ws1, const float* __restrict__ Wn1,
                  ushort* __restrict__ WbT) {
  const int idx = blockIdx.x;            // 0..255 = h*128 + n
  const int h = idx >> 7, n = idx & 127;
  const float* W = h ? Wn1 : Ws1;
  WbT[(size_t)idx * FDIM + threadIdx.x] = f2bf(W[(size_t)threadIdx.x * HDIM + n]);
}

// ---------------- MFMA half: 32x256 (LDS A) @ 256x128 (global bf16 B) ----------------
// relu + column-mean over rows 0..24 (rows 25..31 are exact zeros) -> dst[0..127]
__device__ static inline void mfma_half(const ushort (*As)[32][40],
                                        const ushort* __restrict__ Bmat,
                                        float* __restrict__ dst,
                                        int wave, int lq, int lr) {
  f32x4 acc[2][2];
#pragma unroll
  for (int rt = 0; rt < 2; ++rt)
#pragma unroll
    for (int ct = 0; ct < 2; ++ct) acc[rt][ct] = (f32x4)(0.f);

#pragma unroll
  for (int k0 = 0; k0 < 8; ++k0) {
    bf16x8 b0 = *(const bf16x8*)(Bmat + (size_t)(wave * 32 + lr) * FDIM + k0 * 32 + lq * 8);
    bf16x8 b1 = *(const bf16x8*)(Bmat + (size_t)(wave * 32 + 16 + lr) * FDIM + k0 * 32 + lq * 8);
    bf16x8 a0 = *(const bf16x8*)&As[k0][lr][lq * 8];
    bf16x8 a1 = *(const bf16x8*)&As[k0][16 + lr][lq * 8];
    acc[0][0] = __builtin_amdgcn_mfma_f32_16x16x32_bf16(a0, b0, acc[0][0], 0, 0, 0);
    acc[0][1] = __builtin_amdgcn_mfma_f32_16x16x32_bf16(a0, b1, acc[0][1], 0, 0, 0);
    acc[1][0] = __builtin_amdgcn_mfma_f32_16x16x32_bf16(a1, b0, acc[1][0], 0, 0, 0);
    acc[1][1] = __builtin_amdgcn_mfma_f32_16x16x32_bf16(a1, b1, acc[1][1], 0, 0, 0);
  }

#pragma unroll
  for (int ct = 0; ct < 2; ++ct) {
    float s = 0.f;
#pragma unroll
    for (int rt = 0; rt < 2; ++rt)
#pragma unroll
      for (int r = 0; r < 4; ++r)
        s += fmaxf(acc[rt][ct][r], 0.f);
    s += __shfl_xor(s, 16, 64);
    s += __shfl_xor(s, 32, 64);
    if (lq == 0) dst[wave * 32 + ct * 16 + lr] = s * (1.f / S1);
  }
}

// ================= K2: mega kernel — one block per batch row, 4 blocks/CU ============
// LDS ~29.9 KB (single time-shared A-tile; n2m stashed in registers between halves).
// __launch_bounds__(256,4): VGPR cap 128 — r3's (256,5)=102-cap caused 90 MB of
// scratch spills (WRITE_SIZE counter); 4 blocks/CU = 16 waves/CU with zero spill.
__global__ __launch_bounds__(256, 4)
void mega_kernel(const int* __restrict__ node_ids, const float* __restrict__ feat,
                 const int* __restrict__ adj, const ushort* __restrict__ WbT,
                 const float* __restrict__ Ws1, const float* __restrict__ Wn1,
                 const float* __restrict__ Ws2, const float* __restrict__ Wn2,
                 const float* __restrict__ Wp, const float* __restrict__ bp,
                 float* __restrict__ out,
                 uint32_t kb1_0, uint32_t kb1_1, uint32_t kb2_0, uint32_t kb2_1) {
  const int b = blockIdx.x;
  const int t = threadIdx.x;
  const int wave = t >> 6, lane = t & 63;
  const int lq = lane >> 4, lr = lane & 15;

  __shared__ int    hop1s[S1];
  __shared__ int    hop2s[S1 * S2];
  __shared__ ushort As[8][32][40];    // time-shared: f1 for half0, n2m for half1 (20.5 KB)
  __shared__ float  F0[FDIM];
  __shared__ float  N1[4][FDIM];      // per-wave n1 partials; N1[0] -> combined mean
  __shared__ float  H1M[2 * HDIM];
  __shared__ float  H0[2 * HDIM];
  __shared__ float  HN[2 * HDIM];
  __shared__ float  red[4];
  __shared__ float  lg[NCLS];
  __shared__ float  smx[2];

  const int nid = node_ids[b];

  // ---- A: merged hop1+hop2 sampling (hop1 recomputed redundantly per thread;
  //         the 10 same-s1 adj reads coalesce to one line) + f0 + A-pad zero ----
  if (t < S1 * S2) {
    const int s1 = t / S2;
    uint32_t c1 = rand_bits_at(kb1_0, kb1_1, (uint32_t)(b * S1 + s1)) & (MAXDEG - 1);
    const int h1 = adj[(size_t)nid * MAXDEG + c1];
    if (t == s1 * S2) hop1s[s1] = h1;
    uint32_t c2 = rand_bits_at(kb2_0, kb2_1, (uint32_t)(b * S1 * S2 + t)) & (MAXDEG - 1);
    hop2s[t] = adj[(size_t)h1 * MAXDEG + c2];
  }
  if (t < 64) ((float4*)F0)[t] = ((const float4*)(feat + (size_t)nid * FDIM))[t];
  {
    ushort4 z; z.x = 0; z.y = 0; z.z = 0; z.w = 0;
    for (int i = t; i < 448; i += 256) {   // rows 25..31 x 8 chunks x 8 q-slots
      const int rc = i >> 3, q = i & 7;
      const int r = 25 + (rc >> 3), ch = rc & 7;
      *(ushort4*)&As[ch][r][q * 4] = z;
    }
  }
  __syncthreads();

  // ---- C: gather f1 (-> LDS As + n1 partial) + f2 means (-> register stash nm) ----
  ushort4 nm[7];
  {
    float ax = 0.f, ay = 0.f, az = 0.f, aw = 0.f;
#pragma unroll
    for (int i = 0; i < 7; ++i) {
      const int s1 = wave + i * 4;
      if (s1 < S1) {
        const int rid1 = hop1s[s1];
        float4 v = ((const float4*)(feat + (size_t)rid1 * FDIM))[lane];
        float bx = 0.f, by = 0.f, bz = 0.f, bw = 0.f;
#pragma unroll
        for (int r = 0; r < S2; ++r) {
          const int rid = hop2s[s1 * S2 + r];
          float4 w = ((const float4*)(feat + (size_t)rid * FDIM))[lane];
          bx += w.x; by += w.y; bz += w.z; bw += w.w;
        }
        ax += v.x; ay += v.y; az += v.z; aw += v.w;
        ushort4 o1;
        o1.x = f2bf(v.x); o1.y = f2bf(v.y); o1.z = f2bf(v.z); o1.w = f2bf(v.w);
        *(ushort4*)&As[lane >> 3][s1][(lane & 7) * 4] = o1;
        const float inv2 = 1.f / S2;
        ushort4 o2;
        o2.x = f2bf(bx * inv2); o2.y = f2bf(by * inv2);
        o2.z = f2bf(bz * inv2); o2.w = f2bf(bw * inv2);
        nm[i] = o2;
      }
    }
    float4 p; p.x = ax; p.y = ay; p.z = az; p.w = aw;
    ((float4*)N1[wave])[lane] = p;
  }
  __syncthreads();

  // ---- D0: MFMA half 0 (A = f1) -> H1M[0..127] ----
  mfma_half(As, WbT, H1M, wave, lq, lr);
  __syncthreads();

  // ---- swap: n2m stash -> As; combine n1 mean (thread t owns column t) ----
#pragma unroll
  for (int i = 0; i < 7; ++i) {
    const int s1 = wave + i * 4;
    if (s1 < S1) *(ushort4*)&As[lane >> 3][s1][(lane & 7) * 4] = nm[i];
  }
  {
    const float s = N1[0][t] + N1[1][t] + N1[2][t] + N1[3][t];
    N1[0][t] = s * (1.f / S1);
  }
  __syncthreads();

  // ---- D1: MFMA half 1 (A = n2m) -> H1M[128..255] ----
  mfma_half(As, WbT + (size_t)HDIM * FDIM, H1M + HDIM, wave, lq, lr);
  __syncthreads();

  // ---- E: tail ----
  const int hh = t >> 7, c = t & 127;
  // phase 1: h0 = relu([f0@Ws1 ; n1m@Wn1]), column t
  {
    const float* W = hh ? Wn1 : Ws1;
    const float* Ap = hh ? N1[0] : F0;
    float acc = 0.f;
#pragma unroll 8
    for (int k4 = 0; k4 < 64; ++k4) {
      float4 a = ((const float4*)Ap)[k4];
      acc += a.x * W[(size_t)(k4 * 4 + 0) * HDIM + c]
           + a.y * W[(size_t)(k4 * 4 + 1) * HDIM + c]
           + a.z * W[(size_t)(k4 * 4 + 2) * HDIM + c]
           + a.w * W[(size_t)(k4 * 4 + 3) * HDIM + c];
    }
    H0[t] = fmaxf(acc, 0.f);
  }
  __syncthreads();

  // phase 2: h = [H0@Ws2 ; H1M@Wn2] (no act), column t
  float hv;
  {
    const float* W = hh ? Wn2 : Ws2;
    const float* Ap = hh ? H1M : H0;
    float acc = 0.f;
#pragma unroll 8
    for (int k4 = 0; k4 < 64; ++k4) {
      float4 a = ((const float4*)Ap)[k4];
      acc += a.x * W[(size_t)(k4 * 4 + 0) * HDIM + c]
           + a.y * W[(size_t)(k4 * 4 + 1) * HDIM + c]
           + a.z * W[(size_t)(k4 * 4 + 2) * HDIM + c]
           + a.w * W[(size_t)(k4 * 4 + 3) * HDIM + c];
    }
    hv = acc;
  }

  // phase 3: l2 normalize
  {
    float s = hv * hv;
#pragma unroll
    for (int off = 32; off; off >>= 1) s += __shfl_xor(s, off, 64);
    if (lane == 0) red[wave] = s;
  }
  __syncthreads();
  {
    const float scl = rsqrtf(fmaxf(red[0] + red[1] + red[2] + red[3], 1e-12f));
    HN[t] = hv * scl;
  }
  __syncthreads();

  // phase 4: logits — 41 dot-256's split across 4-lane groups, quad shfl reduce
  {
    const int g = t >> 2, q = t & 3;
    if (g < NCLS) {
      float s = 0.f;
#pragma unroll 8
      for (int k = 0; k < 64; ++k)
        s += HN[q * 64 + k] * Wp[(size_t)(q * 64 + k) * NCLS + g];
      s += __shfl_xor(s, 1, 64);
      s += __shfl_xor(s, 2, 64);
      if (q == 0) lg[g] = s + bp[g];
    }
  }
  __syncthreads();
  if (t == 0) {
    float m = -1e30f;
    for (int i = 0; i < NCLS; ++i) m = fmaxf(m, lg[i]);
    float ssum = 0.f;
    for (int i = 0; i < NCLS; ++i) ssum += expf(lg[i] - m);
    smx[0] = m; smx[1] = ssum;
  }
  __syncthreads();
  if (t < NCLS)
    out[(size_t)b * NCLS + t] = expf(lg[t] - smx[0]) / smx[1];
}

// ================= launch ============================================================
extern "C" void kernel_launch(void* const* d_in, const int* in_sizes, int n_in,
                              void* d_out, int out_size, void* d_ws, size_t ws_size,
                              hipStream_t stream) {
  const int*   node_ids = (const int*)d_in[0];
  const float* features = (const float*)d_in[1];
  const int*   adj      = (const int*)d_in[2];
  const float* Ws1      = (const float*)d_in[3];
  const float* Wn1      = (const float*)d_in[4];
  const float* Ws2      = (const float*)d_in[5];
  const float* Wn2      = (const float*)d_in[6];
  const float* Wp       = (const float*)d_in[7];
  const float* bp       = (const float*)d_in[8];
  float* out = (float*)d_out;

  ushort* WbT = (ushort*)d_ws;                // 2x128x256 bf16 (128 KB) — only ws use

  // JAX threefry key chain (bit-exact, r1-verified)
  uint32_t k1_0, k1_1, k2_0, k2_1, kb1_0, kb1_1, kb2_0, kb2_1;
  tf2x32(0u, 42u, 0u, 0u, k1_0, k1_1);
  tf2x32(0u, 42u, 0u, 1u, k2_0, k2_1);
  tf2x32(k1_0, k1_1, 0u, 1u, kb1_0, kb1_1);
  tf2x32(k2_0, k2_1, 0u, 1u, kb2_0, kb2_1);

  wprep_kernel<<<256, 256, 0, stream>>>(Ws1, Wn1, WbT);

  mega_kernel<<<BATCH, 256, 0, stream>>>(node_ids, features, adj, WbT,
                                         Ws1, Wn1, Ws2, Wn2, Wp, bp, out,
                                         kb1_0, kb1_1, kb2_0, kb2_1);
}

// Round 5
// 358.605 us; speedup vs baseline: 1.1276x; 1.0822x over previous
//
#include <hip/hip_runtime.h>
#include <cstdint>
#include <cstddef>

// Problem constants (from reference)
#define BATCH 1024
#define S1 25
#define S2 10
#define FDIM 256
#define HDIM 128
#define NCLS 41
#define MAXDEG 128

typedef __attribute__((ext_vector_type(8))) short bf16x8;
typedef __attribute__((ext_vector_type(4))) float f32x4;

// ---------------- Threefry-2x32 (bit-exact vs JAX partitionable; r1-verified) --------
__host__ __device__ static inline void tf2x32(uint32_t k0, uint32_t k1,
                                              uint32_t c0, uint32_t c1,
                                              uint32_t& o0, uint32_t& o1) {
  const uint32_t ks2 = k0 ^ k1 ^ 0x1BD11BDAu;
  uint32_t x0 = c0 + k0, x1 = c1 + k1;
#define TFR(r) { x0 += x1; x1 = (x1 << (r)) | (x1 >> (32 - (r))); x1 ^= x0; }
  TFR(13) TFR(15) TFR(26) TFR(6)
  x0 += k1;  x1 += ks2 + 1u;
  TFR(17) TFR(29) TFR(16) TFR(24)
  x0 += ks2; x1 += k0 + 2u;
  TFR(13) TFR(15) TFR(26) TFR(6)
  x0 += k0;  x1 += k1 + 3u;
  TFR(17) TFR(29) TFR(16) TFR(24)
  x0 += k1;  x1 += ks2 + 4u;
  TFR(13) TFR(15) TFR(26) TFR(6)
  x0 += ks2; x1 += k0 + 5u;
#undef TFR
  o0 = x0; o1 = x1;
}

__device__ static inline uint32_t rand_bits_at(uint32_t kb0, uint32_t kb1, uint32_t j) {
  uint32_t o0, o1;
  tf2x32(kb0, kb1, 0u, j, o0, o1);
  return o0 ^ o1;
}

// fp32 -> bf16 (RNE) — values bit-preserved vs previous rounds
__device__ static inline ushort f2bf(float x) {
  uint32_t u = __float_as_uint(x);
  return (ushort)((u + 0x7fffu + ((u >> 16) & 1u)) >> 16);
}

// ================= K1: WbT transpose (2x128 rows of 256 bf16) ========================
__global__ __launch_bounds__(256)
void wprep_kernel(const float* __restrict__ Ws1, const float* __restrict__ Wn1,
                  ushort* __restrict__ WbT) {
  const int idx = blockIdx.x;            // 0..255 = h*128 + n
  const int h = idx >> 7, n = idx & 127;
  const float* W = h ? Wn1 : Ws1;
  WbT[(size_t)idx * FDIM + threadIdx.x] = f2bf(W[(size_t)threadIdx.x * HDIM + n]);
}

// ---------------- MFMA half: 32x256 (LDS A) @ 256x128 (global bf16 B) ----------------
// Rows 0..24: sampled rows -> relu + column-mean/25 -> dstMean[0..127].
// Row 25: extra GEMV row (f0 or n1m) -> relu -> dstH0[0..127]  (excluded from mean).
// Rows 26..31: exact zeros (relu(0)=0, no mean contribution).
// Verified D-layout: out_row = rt*16 + lq*4 + r, out_col = wave*32 + ct*16 + lr.
__device__ static inline void mfma_half(const ushort (*As)[32][40],
                                        const ushort* __restrict__ Bmat,
                                        float* __restrict__ dstMean,
                                        float* __restrict__ dstH0,
                                        int wave, int lq, int lr) {
  f32x4 acc[2][2];
#pragma unroll
  for (int rt = 0; rt < 2; ++rt)
#pragma unroll
    for (int ct = 0; ct < 2; ++ct) acc[rt][ct] = (f32x4)(0.f);

#pragma unroll
  for (int k0 = 0; k0 < 8; ++k0) {
    bf16x8 b0 = *(const bf16x8*)(Bmat + (size_t)(wave * 32 + lr) * FDIM + k0 * 32 + lq * 8);
    bf16x8 b1 = *(const bf16x8*)(Bmat + (size_t)(wave * 32 + 16 + lr) * FDIM + k0 * 32 + lq * 8);
    bf16x8 a0 = *(const bf16x8*)&As[k0][lr][lq * 8];
    bf16x8 a1 = *(const bf16x8*)&As[k0][16 + lr][lq * 8];
    acc[0][0] = __builtin_amdgcn_mfma_f32_16x16x32_bf16(a0, b0, acc[0][0], 0, 0, 0);
    acc[0][1] = __builtin_amdgcn_mfma_f32_16x16x32_bf16(a0, b1, acc[0][1], 0, 0, 0);
    acc[1][0] = __builtin_amdgcn_mfma_f32_16x16x32_bf16(a1, b0, acc[1][0], 0, 0, 0);
    acc[1][1] = __builtin_amdgcn_mfma_f32_16x16x32_bf16(a1, b1, acc[1][1], 0, 0, 0);
  }

#pragma unroll
  for (int ct = 0; ct < 2; ++ct) {
    const int n = wave * 32 + ct * 16 + lr;
    // row 25 (rt=1, lq==2, r==1): the piggybacked GEMV row
    if (lq == 2) dstH0[n] = fmaxf(acc[1][ct][1], 0.f);
    float s = 0.f;
#pragma unroll
    for (int rt = 0; rt < 2; ++rt)
#pragma unroll
      for (int r = 0; r < 4; ++r) {
        float val = fmaxf(acc[rt][ct][r], 0.f);
        if (rt == 1 && r == 1) val = (lq == 2) ? 0.f : val;  // exclude row 25 from mean
        s += val;
      }
    s += __shfl_xor(s, 16, 64);
    s += __shfl_xor(s, 32, 64);
    if (lq == 0) dstMean[n] = s * (1.f / S1);
  }
}

// ================= K2: mega kernel — one block per batch row =========================
// Chain-latency-bound regime (all 1024 blocks co-resident at 4/CU): optimize the
// per-block serial chain. No register state spans an MFMA phase (no spills).
// LDS ~28.5 KB. (256,4): 128 unified VGPR cap, 4 blocks/CU.
__global__ __launch_bounds__(256, 4)
void mega_kernel(const int* __restrict__ node_ids, const float* __restrict__ feat,
                 const int* __restrict__ adj, const ushort* __restrict__ WbT,
                 const float* __restrict__ Ws2, const float* __restrict__ Wn2,
                 const float* __restrict__ Wp, const float* __restrict__ bp,
                 float* __restrict__ out,
                 uint32_t kb1_0, uint32_t kb1_1, uint32_t kb2_0, uint32_t kb2_1) {
  const int b = blockIdx.x;
  const int t = threadIdx.x;
  const int wave = t >> 6, lane = t & 63;
  const int lq = lane >> 4, lr = lane & 15;

  __shared__ int    hop1s[S1];
  __shared__ int    hop2s[S1 * S2];
  __shared__ ushort As[8][32][40];    // time-shared A-tile (20.5 KB)
  __shared__ float  N1[4][FDIM];      // per-wave n1 partials (4 KB)
  __shared__ float  H1M[2 * HDIM];    // mean_s1(h1) halves
  __shared__ float  H0[2 * HDIM];     // relu([f0@Ws1 ; n1m@Wn1]) via MFMA row 25
  __shared__ float  HN[2 * HDIM];
  __shared__ float  red[4];
  __shared__ float  lg[NCLS];
  __shared__ float  smx[2];

  const int nid = node_ids[b];

  // ---- A: sampling + f0 -> As0 row 25 (bf16) + zero rows 26..31 ----
  if (t < S1 * S2) {
    const int s1 = t / S2;
    uint32_t c1 = rand_bits_at(kb1_0, kb1_1, (uint32_t)(b * S1 + s1)) & (MAXDEG - 1);
    const int h1 = adj[(size_t)nid * MAXDEG + c1];
    if (t == s1 * S2) hop1s[s1] = h1;
    uint32_t c2 = rand_bits_at(kb2_0, kb2_1, (uint32_t)(b * S1 * S2 + t)) & (MAXDEG - 1);
    hop2s[t] = adj[(size_t)h1 * MAXDEG + c2];
  }
  if (t < 64) {
    float4 v = ((const float4*)(feat + (size_t)nid * FDIM))[t];
    ushort4 o;
    o.x = f2bf(v.x); o.y = f2bf(v.y); o.z = f2bf(v.z); o.w = f2bf(v.w);
    *(ushort4*)&As[t >> 3][25][(t & 7) * 4] = o;   // elem 4t..4t+3 of row 25
  }
  {
    ushort4 z; z.x = 0; z.y = 0; z.z = 0; z.w = 0;
    for (int i = t; i < 384; i += 256) {   // rows 26..31 x 8 chunks x 8 q-slots
      const int rc = i >> 3, q = i & 7;
      const int r = 26 + (rc >> 3), ch = rc & 7;
      *(ushort4*)&As[ch][r][q * 4] = z;
    }
  }
  __syncthreads();

  // ---- C0: gather f1 (all 7 rows in flight) -> As rows + n1 partials ----
  {
    float4 v[7];
#pragma unroll
    for (int i = 0; i < 7; ++i) {
      const int s1 = wave + i * 4;
      if (s1 < S1) v[i] = ((const float4*)(feat + (size_t)hop1s[s1] * FDIM))[lane];
    }
    float ax = 0.f, ay = 0.f, az = 0.f, aw = 0.f;
#pragma unroll
    for (int i = 0; i < 7; ++i) {
      const int s1 = wave + i * 4;
      if (s1 < S1) {
        ax += v[i].x; ay += v[i].y; az += v[i].z; aw += v[i].w;
        ushort4 o;
        o.x = f2bf(v[i].x); o.y = f2bf(v[i].y); o.z = f2bf(v[i].z); o.w = f2bf(v[i].w);
        *(ushort4*)&As[lane >> 3][s1][(lane & 7) * 4] = o;
      }
    }
    float4 p; p.x = ax; p.y = ay; p.z = az; p.w = aw;
    ((float4*)N1[wave])[lane] = p;
  }
  __syncthreads();

  // ---- D0: MFMA half 0 (A rows = f1, row25 = f0) -> H1M[:128], H0[:128] ----
  mfma_half(As, WbT, H1M, H0, wave, lq, lr);
  __syncthreads();

  // ---- C1: n1m combine -> As row 25 (bf16); gather f2 means -> As rows ----
  {
    const float nv = (N1[0][t] + N1[1][t] + N1[2][t] + N1[3][t]) * (1.f / S1);
    As[t >> 5][25][t & 31] = f2bf(nv);
  }
  for (int i = 0; i < 7; ++i) {
    const int s1 = wave + i * 4;
    if (s1 < S1) {
      float bx = 0.f, by = 0.f, bz = 0.f, bw = 0.f;
#pragma unroll
      for (int r = 0; r < S2; ++r) {
        const int rid = hop2s[s1 * S2 + r];
        float4 w = ((const float4*)(feat + (size_t)rid * FDIM))[lane];
        bx += w.x; by += w.y; bz += w.z; bw += w.w;
      }
      const float inv2 = 1.f / S2;
      ushort4 o;
      o.x = f2bf(bx * inv2); o.y = f2bf(by * inv2);
      o.z = f2bf(bz * inv2); o.w = f2bf(bw * inv2);
      *(ushort4*)&As[lane >> 3][s1][(lane & 7) * 4] = o;
    }
  }
  __syncthreads();

  // ---- D1: MFMA half 1 (A rows = f2-means, row25 = n1m) -> H1M[128:], H0[128:] ----
  mfma_half(As, WbT + (size_t)HDIM * FDIM, H1M + HDIM, H0 + HDIM, wave, lq, lr);
  __syncthreads();

  // ---- E: tail ----
  const int hh = t >> 7, c = t & 127;
  // layer 2: h = [H0@Ws2 ; H1M@Wn2] (no act), column t — fp32
  float hv;
  {
    const float* W = hh ? Wn2 : Ws2;
    const float* Ap = hh ? H1M : H0;
    float acc = 0.f;
#pragma unroll 8
    for (int k4 = 0; k4 < 64; ++k4) {
      float4 a = ((const float4*)Ap)[k4];
      acc += a.x * W[(size_t)(k4 * 4 + 0) * HDIM + c]
           + a.y * W[(size_t)(k4 * 4 + 1) * HDIM + c]
           + a.z * W[(size_t)(k4 * 4 + 2) * HDIM + c]
           + a.w * W[(size_t)(k4 * 4 + 3) * HDIM + c];
    }
    hv = acc;
  }

  // l2 normalize
  {
    float s = hv * hv;
#pragma unroll
    for (int off = 32; off; off >>= 1) s += __shfl_xor(s, off, 64);
    if (lane == 0) red[wave] = s;
  }
  __syncthreads();
  {
    const float scl = rsqrtf(fmaxf(red[0] + red[1] + red[2] + red[3], 1e-12f));
    HN[t] = hv * scl;
  }
  __syncthreads();

  // logits — 41 dot-256's split across 4-lane groups, quad shfl reduce
  {
    const int g = t >> 2, q = t & 3;
    if (g < NCLS) {
      float s = 0.f;
#pragma unroll 8
      for (int k = 0; k < 64; ++k)
        s += HN[q * 64 + k] * Wp[(size_t)(q * 64 + k) * NCLS + g];
      s += __shfl_xor(s, 1, 64);
      s += __shfl_xor(s, 2, 64);
      if (q == 0) lg[g] = s + bp[g];
    }
  }
  __syncthreads();
  if (t == 0) {
    float m = -1e30f;
    for (int i = 0; i < NCLS; ++i) m = fmaxf(m, lg[i]);
    float ssum = 0.f;
    for (int i = 0; i < NCLS; ++i) ssum += expf(lg[i] - m);
    smx[0] = m; smx[1] = ssum;
  }
  __syncthreads();
  if (t < NCLS)
    out[(size_t)b * NCLS + t] = expf(lg[t] - smx[0]) / smx[1];
}

// ================= launch ============================================================
extern "C" void kernel_launch(void* const* d_in, const int* in_sizes, int n_in,
                              void* d_out, int out_size, void* d_ws, size_t ws_size,
                              hipStream_t stream) {
  const int*   node_ids = (const int*)d_in[0];
  const float* features = (const float*)d_in[1];
  const int*   adj      = (const int*)d_in[2];
  const float* Ws1      = (const float*)d_in[3];
  const float* Wn1      = (const float*)d_in[4];
  const float* Ws2      = (const float*)d_in[5];
  const float* Wn2      = (const float*)d_in[6];
  const float* Wp       = (const float*)d_in[7];
  const float* bp       = (const float*)d_in[8];
  float* out = (float*)d_out;

  ushort* WbT = (ushort*)d_ws;                // 2x128x256 bf16 (128 KB) — only ws use

  // JAX threefry key chain (bit-exact, r1-verified)
  uint32_t k1_0, k1_1, k2_0, k2_1, kb1_0, kb1_1, kb2_0, kb2_1;
  tf2x32(0u, 42u, 0u, 0u, k1_0, k1_1);
  tf2x32(0u, 42u, 0u, 1u, k2_0, k2_1);
  tf2x32(k1_0, k1_1, 0u, 1u, kb1_0, kb1_1);
  tf2x32(k2_0, k2_1, 0u, 1u, kb2_0, kb2_1);

  wprep_kernel<<<256, 256, 0, stream>>>(Ws1, Wn1, WbT);

  mega_kernel<<<BATCH, 256, 0, stream>>>(node_ids, features, adj, WbT,
                                         Ws2, Wn2, Wp, bp, out,
                                         kb1_0, kb1_1, kb2_0, kb2_1);
}